// Round 11
// baseline (795.065 us; speedup 1.0000x reference)
//
#include <hip/hip_runtime.h>
#include <hip/hip_bf16.h>
#include <math.h>

#define T_TOK 8192
#define H_DIM 1024
#define I_DIM 2816
#define N_EXP 8
#define NREG  16           // (expert, k) regions
#define CAP_SLOTS 18432    // 2*T + 16*128 alignment headroom
#define MAX_TILES 144      // CAP_SLOTS / 128
#define SD_ROW 14336       // shared_down bf16 parked in hid rows [14336..15360)

typedef __bf16 bf16x8 __attribute__((ext_vector_type(8)));
typedef __bf16 bf16x4 __attribute__((ext_vector_type(4)));
typedef float f32x4 __attribute__((ext_vector_type(4)));

__device__ inline void gload_lds16(const void* g, void* l) {
    __builtin_amdgcn_global_load_lds((const __attribute__((address_space(1))) void*)g,
                                     (__attribute__((address_space(3))) void*)l, 16, 0, 0);
}

// Bijective XCD-aware tile swizzle (m204).
__device__ inline void swz_tile(int& bx, int& by) {
    const int nx = gridDim.x;
    const int nwg = nx * gridDim.y;
    int lin = by * nx + bx;
    int q = nwg >> 3, r = nwg & 7, xcd = lin & 7, pos = lin >> 3;
    int swz = (xcd < r ? xcd * (q + 1) : r * (q + 1) + (xcd - r) * q) + pos;
    bx = swz % nx; by = swz / nx;
}

__device__ inline void conv4(const float* __restrict__ src, __bf16* __restrict__ dst, int i) {
    float4 v = ((const float4*)src)[i];
    bf16x4 o;
    o[0] = (__bf16)v.x; o[1] = (__bf16)v.y; o[2] = (__bf16)v.z; o[3] = (__bf16)v.w;
    ((bf16x4*)dst)[i] = o;
}

// f32 -> bf16 standalone (expert_down)
__global__ void conv_kernel(const float* __restrict__ src, __bf16* __restrict__ dst, int n4) {
    int i = blockIdx.x * 256 + threadIdx.x;
    if (i < n4) conv4(src, dst, i);
}

// Router body: one wave per token, logits over 8 experts, softmax, top-2. No atomics.
__device__ void router_body(int t, int lane, const float* __restrict__ x,
                            const float* __restrict__ gw,
                            int* __restrict__ topi, float* __restrict__ topw) {
    const float4* xr = (const float4*)(x + (size_t)t * H_DIM);
    float s[N_EXP];
#pragma unroll
    for (int e = 0; e < N_EXP; e++) s[e] = 0.0f;
#pragma unroll
    for (int j = 0; j < H_DIM / 256; ++j) {
        float4 xv = xr[j * 64 + lane];
#pragma unroll
        for (int e = 0; e < N_EXP; e++) {
            float4 gv = ((const float4*)(gw + (size_t)e * H_DIM))[j * 64 + lane];
            s[e] += xv.x * gv.x + xv.y * gv.y + xv.z * gv.z + xv.w * gv.w;
        }
    }
#pragma unroll
    for (int off = 32; off; off >>= 1) {
#pragma unroll
        for (int e = 0; e < N_EXP; e++) s[e] += __shfl_xor(s[e], off);
    }
    if (lane == 0) {
        float m = s[0];
#pragma unroll
        for (int e = 1; e < N_EXP; e++) m = fmaxf(m, s[e]);
        float p[N_EXP]; float sum = 0.0f;
#pragma unroll
        for (int e = 0; e < N_EXP; e++) { p[e] = expf(s[e] - m); sum += p[e]; }
#pragma unroll
        for (int e = 0; e < N_EXP; e++) p[e] /= sum;
        int i0 = 0;
#pragma unroll
        for (int e = 1; e < N_EXP; e++) if (p[e] > p[i0]) i0 = e;
        int i1 = (i0 == 0) ? 1 : 0;
#pragma unroll
        for (int e = 0; e < N_EXP; e++) if (e != i0 && p[e] > p[i1]) i1 = e;
        float rs = p[i0] + p[i1] + 1e-20f;
        topi[t * 2 + 0] = i0; topi[t * 2 + 1] = i1;
        topw[t * 2 + 0] = p[i0] / rs; topw[t * 2 + 1] = p[i1] / rs;
    }
}

// Mega-prep: x-conv | router | sg-conv | su-conv | sd-conv, one dispatch.
#define PB_X   8192    // T*H/4/256
#define PB_RT  2048    // T/4
#define PB_C   2816    // I*H/4/256
__global__ void prep_kernel(const float* __restrict__ x, const float* __restrict__ gw,
                            __bf16* __restrict__ xb,
                            int* __restrict__ topi, float* __restrict__ topw,
                            const float* __restrict__ sg, const float* __restrict__ su,
                            const float* __restrict__ sd,
                            __bf16* __restrict__ wA, __bf16* __restrict__ wB,
                            __bf16* __restrict__ sdbuf) {
    int blk = blockIdx.x, tid = threadIdx.x;
    if (blk < PB_X) {
        conv4(x, xb, blk * 256 + tid);
    } else if (blk < PB_X + PB_RT) {
        int t = (blk - PB_X) * 4 + (tid >> 6);
        router_body(t, tid & 63, x, gw, topi, topw);
    } else if (blk < PB_X + PB_RT + PB_C) {
        conv4(sg, wA, (blk - PB_X - PB_RT) * 256 + tid);
    } else if (blk < PB_X + PB_RT + 2 * PB_C) {
        conv4(su, wB, (blk - PB_X - PB_RT - PB_C) * 256 + tid);
    } else {
        conv4(sd, sdbuf, (blk - PB_X - PB_RT - 2 * PB_C) * 256 + tid);
    }
}

// Single-wave routing build: histogram -> bases -> tiles -> slots (+ slot_of inverse).
__global__ void route_build_kernel(const int* __restrict__ topi, const float* __restrict__ topw,
                                   int* __restrict__ token_ids, float* __restrict__ token_w,
                                   int* __restrict__ slot_of,
                                   int* __restrict__ tile_e, int* __restrict__ tile_k) {
    __shared__ int h[64][NREG];
    __shared__ int bases[NREG];
    __shared__ int cur[64][NREG];
    const int lane = threadIdx.x;   // 0..63, single wave

    for (int i = lane; i < CAP_SLOTS; i += 64) token_ids[i] = -1;

#pragma unroll
    for (int r = 0; r < NREG; r++) h[lane][r] = 0;
    for (int i = 0; i < T_TOK * 2 / 64; i++) {
        int entry = i * 64 + lane;
        int r = topi[entry] * 2 + (entry & 1);
        h[lane][r]++;
    }
    __syncthreads();

    if (lane < NREG) {
        int c = 0;
        for (int l = 0; l < 64; l++) c += h[l][lane];
        bases[lane] = c;
    }
    __syncthreads();

    if (lane == 0) {
        int b = 0, t = 0;
        for (int r = 0; r < NREG; r++) {
            int c = bases[r];
            int nt = (c + 127) >> 7;
            bases[r] = b;
            for (int i = 0; i < nt; i++) { tile_e[t] = r >> 1; tile_k[t] = r & 1; t++; }
            b += nt << 7;
        }
        for (; t < MAX_TILES; t++) { tile_e[t] = -1; tile_k[t] = -1; }
    }
    __syncthreads();

    for (int r = 0; r < NREG; r++) {
        int s = bases[r];
        for (int l = 0; l < lane; l++) s += h[l][r];
        cur[lane][r] = s;
    }
    __syncthreads();

    for (int i = 0; i < T_TOK * 2 / 64; i++) {
        int entry = i * 64 + lane;
        int r = topi[entry] * 2 + (entry & 1);
        int slot = cur[lane][r]++;
        token_ids[slot] = entry >> 1;
        token_w[slot] = topw[entry];
        slot_of[entry] = slot;
    }
}

// out[t][h] += w0*r_out[s0][h] + w1*r_out[s1][h]
__global__ void combine_kernel(float* __restrict__ out, const __bf16* __restrict__ r_out,
                               const int* __restrict__ slot_of, const float* __restrict__ topw) {
    int gid = blockIdx.x * 256 + threadIdx.x;
    int t = gid >> 8;
    int hcol = (gid & 255) * 4;
    int s0 = slot_of[t * 2], s1 = slot_of[t * 2 + 1];
    float w0 = topw[t * 2], w1 = topw[t * 2 + 1];
    bf16x4 a = *(const bf16x4*)&r_out[(size_t)s0 * H_DIM + hcol];
    bf16x4 b = *(const bf16x4*)&r_out[(size_t)s1 * H_DIM + hcol];
    float4 o = *(float4*)&out[(size_t)t * H_DIM + hcol];
    o.x += w0 * (float)a[0] + w1 * (float)b[0];
    o.y += w0 * (float)a[1] + w1 * (float)b[1];
    o.z += w0 * (float)a[2] + w1 * (float)b[2];
    o.w += w0 * (float)a[3] + w1 * (float)b[3];
    *(float4*)&out[(size_t)t * H_DIM + hcol] = o;
}

// Fused gate+up GEMM (R8-proven): 128x128, BK=32, 8 waves of 64x32 on both mats.
template<int K>
__global__ __launch_bounds__(512, 3)
void gateup_fused(const __bf16* __restrict__ A,
                  const __bf16* __restrict__ Wg, const __bf16* __restrict__ Wu,
                  __bf16* __restrict__ hid,
                  const int* __restrict__ token_ids, const int* __restrict__ tile_e) {
    int bx = blockIdx.x, by = blockIdx.y;
    swz_tile(bx, by);
    int e = 0;
    if (tile_e) { e = tile_e[bx]; if (e < 0) return; }
    const int m0 = bx * 128, n0 = by * 128;

    __shared__ __bf16 As[2][128 * 32];
    __shared__ __bf16 Bg[2][128 * 32];
    __shared__ __bf16 Bu[2][128 * 32];

    const int tid = threadIdx.x, lane = tid & 63, wid = tid >> 6;
    const int wm = wid >> 2, wn = wid & 3;

    const int srow = tid >> 2;
    const int colb = (tid & 3) * 16;

    int ar;
    if (tile_e) {
        int t0 = token_ids[m0 + srow];
        ar = t0 < 0 ? 0 : t0;
    } else {
        ar = m0 + srow;
    }
    const char* pA = (const char*)A + (size_t)ar * (K * 2) + colb;
    const char* pG = (const char*)Wg + ((size_t)e * I_DIM + n0 + srow) * (K * 2) + colb;
    const char* pU = (const char*)Wu + ((size_t)e * I_DIM + n0 + srow) * (K * 2) + colb;
    const int ldsoff = wid * 1024;

    f32x4 accg[4][2], accu[4][2];
    const f32x4 z4 = {0.f, 0.f, 0.f, 0.f};
#pragma unroll
    for (int i = 0; i < 4; i++)
#pragma unroll
        for (int j = 0; j < 2; j++) { accg[i][j] = z4; accu[i][j] = z4; }

    constexpr int NT = K / 32;

    auto stage = [&](int buf, int kt) {
        const size_t ko = (size_t)kt * 64;
        gload_lds16(pA + ko, (char*)As[buf] + ldsoff);
        gload_lds16(pG + ko, (char*)Bg[buf] + ldsoff);
        gload_lds16(pU + ko, (char*)Bu[buf] + ldsoff);
    };

    auto compute = [&](int buf) {
        const int rA = wm * 64 + (lane & 15);
        const int rB = wn * 32 + (lane & 15);
        const int cK = (lane >> 4) * 8;
        bf16x8 a[4], g[2], u[2];
#pragma unroll
        for (int i = 0; i < 4; i++) a[i] = *(const bf16x8*)&As[buf][(rA + i * 16) * 32 + cK];
#pragma unroll
        for (int j = 0; j < 2; j++) {
            g[j] = *(const bf16x8*)&Bg[buf][(rB + j * 16) * 32 + cK];
            u[j] = *(const bf16x8*)&Bu[buf][(rB + j * 16) * 32 + cK];
        }
#pragma unroll
        for (int i = 0; i < 4; i++)
#pragma unroll
            for (int j = 0; j < 2; j++) {
                accg[i][j] = __builtin_amdgcn_mfma_f32_16x16x32_bf16(a[i], g[j], accg[i][j], 0, 0, 0);
                accu[i][j] = __builtin_amdgcn_mfma_f32_16x16x32_bf16(a[i], u[j], accu[i][j], 0, 0, 0);
            }
    };

    stage(0, 0);
    __syncthreads();
    int cur = 0;
    for (int kt = 0; kt < NT; ++kt) {
        if (kt + 1 < NT) stage(cur ^ 1, kt + 1);
        compute(cur);
        __syncthreads();
        cur ^= 1;
    }

    const int cb = lane & 15, rb = (lane >> 4) * 4;
#pragma unroll
    for (int i = 0; i < 4; i++)
#pragma unroll
        for (int j = 0; j < 2; j++)
#pragma unroll
            for (int r = 0; r < 4; r++) {
                const int row = wm * 64 + i * 16 + rb + r;
                const int col = n0 + wn * 32 + j * 16 + cb;
                float gv = accg[i][j][r];
                float uv = accu[i][j][r];
                float h = (gv / (1.0f + __expf(-gv))) * uv;
                hid[(size_t)(m0 + row) * I_DIM + col] = (__bf16)h;
            }
}

// Shared-down GEMM merged with eg/eu weight conversion (independent work, one dispatch).
#define DC_CB 22528   // N_EXP*I*H/4/256
__global__ __launch_bounds__(256, 4)
void downsh_conv_kernel(const float* __restrict__ eg, const float* __restrict__ eu,
                        __bf16* __restrict__ wA, __bf16* __restrict__ wB,
                        const __bf16* __restrict__ hid, const __bf16* __restrict__ sdw,
                        float* __restrict__ out) {
    __shared__ __bf16 As[2][128 * 32];
    __shared__ __bf16 Bs[2][128 * 32];
    const int blk = blockIdx.x, tid = threadIdx.x;
    if (blk < DC_CB) { conv4(eg, wA, blk * 256 + tid); return; }
    if (blk < 2 * DC_CB) { conv4(eu, wB, (blk - DC_CB) * 256 + tid); return; }

    // shared-expert down: 64 m-tiles x 8 n-tiles, KDIM = I_DIM
    const int t = blk - 2 * DC_CB;
    const int m0 = (t & 63) * 128, n0 = (t >> 6) * 128;
    const int lane = tid & 63, wid = tid >> 6;
    const int wm = wid >> 1, wn = wid & 1;
    const int srow = wid * 16 + (lane >> 2);
    const int colb = (lane & 3) * 16;

    const char* pA0 = (const char*)hid + (size_t)(m0 + srow) * (I_DIM * 2) + colb;
    const char* pA1 = (const char*)hid + (size_t)(m0 + srow + 64) * (I_DIM * 2) + colb;
    const char* pB0 = (const char*)sdw + (size_t)(n0 + srow) * (I_DIM * 2) + colb;
    const char* pB1 = pB0 + (size_t)64 * (I_DIM * 2);
    const int ldsoff = wid * 1024;

    f32x4 acc[4][4];
    const f32x4 z4 = {0.f, 0.f, 0.f, 0.f};
#pragma unroll
    for (int i = 0; i < 4; i++)
#pragma unroll
        for (int j = 0; j < 4; j++) acc[i][j] = z4;

    constexpr int NT = I_DIM / 32;
    auto stage = [&](int buf, int kt) {
        const size_t ko = (size_t)kt * 64;
        char* a_l = (char*)As[buf] + ldsoff;
        gload_lds16(pA0 + ko, a_l);
        gload_lds16(pA1 + ko, a_l + 4096);
        char* b_l = (char*)Bs[buf] + ldsoff;
        gload_lds16(pB0 + ko, b_l);
        gload_lds16(pB1 + ko, b_l + 4096);
    };
    auto compute = [&](int buf) {
        const int rA = wm * 64 + (lane & 15);
        const int rB = wn * 64 + (lane & 15);
        const int cK = (lane >> 4) * 8;
        bf16x8 a[4], b[4];
#pragma unroll
        for (int i = 0; i < 4; i++) a[i] = *(const bf16x8*)&As[buf][(rA + i * 16) * 32 + cK];
#pragma unroll
        for (int j = 0; j < 4; j++) b[j] = *(const bf16x8*)&Bs[buf][(rB + j * 16) * 32 + cK];
#pragma unroll
        for (int i = 0; i < 4; i++)
#pragma unroll
            for (int j = 0; j < 4; j++)
                acc[i][j] = __builtin_amdgcn_mfma_f32_16x16x32_bf16(a[i], b[j], acc[i][j], 0, 0, 0);
    };

    stage(0, 0);
    __syncthreads();
    int cur = 0;
    for (int kt = 0; kt < NT; ++kt) {
        if (kt + 1 < NT) stage(cur ^ 1, kt + 1);
        compute(cur);
        __syncthreads();
        cur ^= 1;
    }

    const int cb = lane & 15, rb = (lane >> 4) * 4;
#pragma unroll
    for (int i = 0; i < 4; i++)
#pragma unroll
        for (int j = 0; j < 4; j++)
#pragma unroll
            for (int r = 0; r < 4; r++) {
                const int row = wm * 64 + i * 16 + rb + r;
                const int col = n0 + wn * 64 + j * 16 + cb;
                out[(size_t)(m0 + row) * H_DIM + col] = acc[i][j][r];
            }
}

// Routed down (R9-proven, EPI3): bf16 slot rows into r_out, XCD swizzle.
__global__ __launch_bounds__(256, 4)
void downrt_kernel(const __bf16* __restrict__ A, const __bf16* __restrict__ B,
                   __bf16* __restrict__ r_out, const int* __restrict__ tile_e) {
    int bx = blockIdx.x, by = blockIdx.y;
    swz_tile(bx, by);
    int e = tile_e[bx];
    if (e < 0) return;
    const int m0 = bx * 128, n0 = by * 128;

    __shared__ __bf16 As[2][128 * 32];
    __shared__ __bf16 Bs[2][128 * 32];

    const int tid = threadIdx.x, lane = tid & 63, wid = tid >> 6;
    const int wm = wid >> 1, wn = wid & 1;
    const int srow = wid * 16 + (lane >> 2);
    const int colb = (lane & 3) * 16;

    const char* pA0 = (const char*)A + (size_t)(m0 + srow) * (I_DIM * 2) + colb;
    const char* pA1 = (const char*)A + (size_t)(m0 + srow + 64) * (I_DIM * 2) + colb;
    const char* pB0 = (const char*)B + ((size_t)e * H_DIM + n0 + srow) * (I_DIM * 2) + colb;
    const char* pB1 = pB0 + (size_t)64 * (I_DIM * 2);
    const int ldsoff = wid * 1024;

    f32x4 acc[4][4];
    const f32x4 z4 = {0.f, 0.f, 0.f, 0.f};
#pragma unroll
    for (int i = 0; i < 4; i++)
#pragma unroll
        for (int j = 0; j < 4; j++) acc[i][j] = z4;

    constexpr int NT = I_DIM / 32;
    auto stage = [&](int buf, int kt) {
        const size_t ko = (size_t)kt * 64;
        char* a_l = (char*)As[buf] + ldsoff;
        gload_lds16(pA0 + ko, a_l);
        gload_lds16(pA1 + ko, a_l + 4096);
        char* b_l = (char*)Bs[buf] + ldsoff;
        gload_lds16(pB0 + ko, b_l);
        gload_lds16(pB1 + ko, b_l + 4096);
    };
    auto compute = [&](int buf) {
        const int rA = wm * 64 + (lane & 15);
        const int rB = wn * 64 + (lane & 15);
        const int cK = (lane >> 4) * 8;
        bf16x8 a[4], b[4];
#pragma unroll
        for (int i = 0; i < 4; i++) a[i] = *(const bf16x8*)&As[buf][(rA + i * 16) * 32 + cK];
#pragma unroll
        for (int j = 0; j < 4; j++) b[j] = *(const bf16x8*)&Bs[buf][(rB + j * 16) * 32 + cK];
#pragma unroll
        for (int i = 0; i < 4; i++)
#pragma unroll
            for (int j = 0; j < 4; j++)
                acc[i][j] = __builtin_amdgcn_mfma_f32_16x16x32_bf16(a[i], b[j], acc[i][j], 0, 0, 0);
    };

    stage(0, 0);
    __syncthreads();
    int cur = 0;
    for (int kt = 0; kt < NT; ++kt) {
        if (kt + 1 < NT) stage(cur ^ 1, kt + 1);
        compute(cur);
        __syncthreads();
        cur ^= 1;
    }

    const int cb = lane & 15, rb = (lane >> 4) * 4;
#pragma unroll
    for (int i = 0; i < 4; i++)
#pragma unroll
        for (int j = 0; j < 4; j++)
#pragma unroll
            for (int r = 0; r < 4; r++) {
                const int row = wm * 64 + i * 16 + rb + r;
                const int col = n0 + wn * 64 + j * 16 + cb;
                r_out[(size_t)(m0 + row) * H_DIM + col] = (__bf16)acc[i][j][r];
            }
}

extern "C" void kernel_launch(void* const* d_in, const int* in_sizes, int n_in,
                              void* d_out, int out_size, void* d_ws, size_t ws_size,
                              hipStream_t stream) {
    const float* x = (const float*)d_in[0];
    const float* gate_w = (const float*)d_in[1];
    const float* expert_gate = (const float*)d_in[2];
    const float* expert_up = (const float*)d_in[3];
    const float* expert_down = (const float*)d_in[4];
    const float* shared_gate = (const float*)d_in[5];
    const float* shared_up = (const float*)d_in[6];
    const float* shared_down = (const float*)d_in[7];
    float* out = (float*)d_out;

    char* w = (char*)d_ws;
    size_t off = 0;
    auto alloc = [&](size_t bytes) {
        void* p = w + off;
        off = (off + bytes + 255) & ~(size_t)255;
        return p;
    };

    // Layout identical to R9 (ws >= this proven by R7-R9 passing).
    const size_t wsz = (size_t)N_EXP * I_DIM * H_DIM * 2;   // 46.1 MB
    __bf16* xb = (__bf16*)alloc((size_t)T_TOK * H_DIM * 2);
    __bf16* wbufA = (__bf16*)alloc(wsz);
    __bf16* hid = (__bf16*)alloc((size_t)CAP_SLOTS * I_DIM * 2);
    int* topi = (int*)alloc((size_t)T_TOK * 2 * 4);
    float* topw = (float*)alloc((size_t)T_TOK * 2 * 4);
    int* slot_of = (int*)alloc((size_t)T_TOK * 2 * 4);
    int* tile_e = (int*)alloc(MAX_TILES * 4);
    int* tile_k = (int*)alloc(MAX_TILES * 4);
    int* token_ids = (int*)alloc((size_t)CAP_SLOTS * 4);
    float* token_w = (float*)alloc((size_t)CAP_SLOTS * 4);
    __bf16* wbufB = (__bf16*)alloc(wsz);
    __bf16* r_out = wbufB;                                  // eu dead after routed gateup
    // shared_down bf16 parked in hid rows [SD_ROW, SD_ROW+1024): written in prep,
    // read by downsh (before routed gateup overwrites hid rows).
    __bf16* sdbuf = hid + (size_t)SD_ROW * I_DIM;

    // 1) prep: x-conv | router | sg | su | sd  (one dispatch)
    prep_kernel<<<PB_X + PB_RT + 3 * PB_C, 256, 0, stream>>>(
        x, gate_w, xb, topi, topw, shared_gate, shared_up, shared_down,
        wbufA, wbufB, sdbuf);

    // 2) routing build
    route_build_kernel<<<1, 64, 0, stream>>>(topi, topw, token_ids, token_w, slot_of, tile_e, tile_k);

    // 3) shared gate+up (wbufA=sg, wbufB=su; identity rows)
    gateup_fused<H_DIM><<<dim3(T_TOK / 128, I_DIM / 128), 512, 0, stream>>>(
        xb, wbufA, wbufB, hid, nullptr, nullptr);

    // 4) shared down (reads hid[0..8192), sdbuf) MERGED with eg/eu conversions
    downsh_conv_kernel<<<2 * DC_CB + 64 * (H_DIM / 128), 256, 0, stream>>>(
        expert_gate, expert_up, wbufA, wbufB, hid, sdbuf, out);

    // 5) routed gate+up (gathered rows)
    gateup_fused<H_DIM><<<dim3(MAX_TILES, I_DIM / 128), 512, 0, stream>>>(
        xb, wbufA, wbufB, hid, token_ids, tile_e);

    // 6) expert_down -> bf16 (wbufA free: eg dead)
    conv_kernel<<<DC_CB, 256, 0, stream>>>(expert_down, wbufA, N_EXP * I_DIM * H_DIM / 4);

    // 7) routed down -> r_out slot rows (single pass, no atomics)
    downrt_kernel<<<dim3(MAX_TILES, H_DIM / 128), 256, 0, stream>>>(hid, wbufA, r_out, tile_e);

    // 8) combine: out += w0*r0 + w1*r1
    combine_kernel<<<T_TOK * H_DIM / 1024, 256, 0, stream>>>(out, r_out, slot_of, topw);
}

// Round 12
// 779.469 us; speedup vs baseline: 1.0200x; 1.0200x over previous
//
#include <hip/hip_runtime.h>
#include <hip/hip_bf16.h>
#include <math.h>

#define T_TOK 8192
#define H_DIM 1024
#define I_DIM 2816
#define N_EXP 8
#define NREG  16           // (expert, k) regions
#define CAP_SLOTS 18432    // 2*T + 16*128 alignment headroom
#define MAX_TILES 144      // CAP_SLOTS / 128
#define SD_ROW 14336       // shared_down bf16 parked in hid rows [14336..15360)

typedef __bf16 bf16x8 __attribute__((ext_vector_type(8)));
typedef __bf16 bf16x4 __attribute__((ext_vector_type(4)));
typedef float f32x4 __attribute__((ext_vector_type(4)));

__device__ inline void gload_lds16(const void* g, void* l) {
    __builtin_amdgcn_global_load_lds((const __attribute__((address_space(1))) void*)g,
                                     (__attribute__((address_space(3))) void*)l, 16, 0, 0);
}

// Bijective XCD-aware tile swizzle (m204).
__device__ inline void swz_tile(int& bx, int& by) {
    const int nx = gridDim.x;
    const int nwg = nx * gridDim.y;
    int lin = by * nx + bx;
    int q = nwg >> 3, r = nwg & 7, xcd = lin & 7, pos = lin >> 3;
    int swz = (xcd < r ? xcd * (q + 1) : r * (q + 1) + (xcd - r) * q) + pos;
    bx = swz % nx; by = swz / nx;
}

__device__ inline void conv4(const float* __restrict__ src, __bf16* __restrict__ dst, int i) {
    float4 v = ((const float4*)src)[i];
    bf16x4 o;
    o[0] = (__bf16)v.x; o[1] = (__bf16)v.y; o[2] = (__bf16)v.z; o[3] = (__bf16)v.w;
    ((bf16x4*)dst)[i] = o;
}

// f32 -> bf16 standalone (expert_down), lean: no LDS, high occupancy
__global__ void conv_kernel(const float* __restrict__ src, __bf16* __restrict__ dst, int n4) {
    int i = blockIdx.x * 256 + threadIdx.x;
    if (i < n4) conv4(src, dst, i);
}

// two-segment lean conv (eg, eu) in one dispatch
__global__ void conv2_kernel(const float* __restrict__ s0, __bf16* __restrict__ d0, int n40,
                             const float* __restrict__ s1, __bf16* __restrict__ d1, int n41) {
    int b0 = (n40 + 255) >> 8;
    const float* src; __bf16* dst; int i;
    if ((int)blockIdx.x < b0) { src = s0; dst = d0; i = blockIdx.x * 256 + threadIdx.x; if (i >= n40) return; }
    else { src = s1; dst = d1; i = (blockIdx.x - b0) * 256 + threadIdx.x; if (i >= n41) return; }
    conv4(src, dst, i);
}

// Router body: one wave per token, logits over 8 experts, softmax, top-2. No atomics.
__device__ void router_body(int t, int lane, const float* __restrict__ x,
                            const float* __restrict__ gw,
                            int* __restrict__ topi, float* __restrict__ topw) {
    const float4* xr = (const float4*)(x + (size_t)t * H_DIM);
    float s[N_EXP];
#pragma unroll
    for (int e = 0; e < N_EXP; e++) s[e] = 0.0f;
#pragma unroll
    for (int j = 0; j < H_DIM / 256; ++j) {
        float4 xv = xr[j * 64 + lane];
#pragma unroll
        for (int e = 0; e < N_EXP; e++) {
            float4 gv = ((const float4*)(gw + (size_t)e * H_DIM))[j * 64 + lane];
            s[e] += xv.x * gv.x + xv.y * gv.y + xv.z * gv.z + xv.w * gv.w;
        }
    }
#pragma unroll
    for (int off = 32; off; off >>= 1) {
#pragma unroll
        for (int e = 0; e < N_EXP; e++) s[e] += __shfl_xor(s[e], off);
    }
    if (lane == 0) {
        float m = s[0];
#pragma unroll
        for (int e = 1; e < N_EXP; e++) m = fmaxf(m, s[e]);
        float p[N_EXP]; float sum = 0.0f;
#pragma unroll
        for (int e = 0; e < N_EXP; e++) { p[e] = expf(s[e] - m); sum += p[e]; }
#pragma unroll
        for (int e = 0; e < N_EXP; e++) p[e] /= sum;
        int i0 = 0;
#pragma unroll
        for (int e = 1; e < N_EXP; e++) if (p[e] > p[i0]) i0 = e;
        int i1 = (i0 == 0) ? 1 : 0;
#pragma unroll
        for (int e = 0; e < N_EXP; e++) if (e != i0 && p[e] > p[i1]) i1 = e;
        float rs = p[i0] + p[i1] + 1e-20f;
        topi[t * 2 + 0] = i0; topi[t * 2 + 1] = i1;
        topw[t * 2 + 0] = p[i0] / rs; topw[t * 2 + 1] = p[i1] / rs;
    }
}

// Mega-prep: x-conv | router | sg-conv | su-conv | sd-conv, one dispatch (no LDS).
#define PB_X   8192    // T*H/4/256
#define PB_RT  2048    // T/4
#define PB_C   2816    // I*H/4/256
__global__ void prep_kernel(const float* __restrict__ x, const float* __restrict__ gw,
                            __bf16* __restrict__ xb,
                            int* __restrict__ topi, float* __restrict__ topw,
                            const float* __restrict__ sg, const float* __restrict__ su,
                            const float* __restrict__ sd,
                            __bf16* __restrict__ wA, __bf16* __restrict__ wB,
                            __bf16* __restrict__ sdbuf) {
    int blk = blockIdx.x, tid = threadIdx.x;
    if (blk < PB_X) {
        conv4(x, xb, blk * 256 + tid);
    } else if (blk < PB_X + PB_RT) {
        int t = (blk - PB_X) * 4 + (tid >> 6);
        router_body(t, tid & 63, x, gw, topi, topw);
    } else if (blk < PB_X + PB_RT + PB_C) {
        conv4(sg, wA, (blk - PB_X - PB_RT) * 256 + tid);
    } else if (blk < PB_X + PB_RT + 2 * PB_C) {
        conv4(su, wB, (blk - PB_X - PB_RT - PB_C) * 256 + tid);
    } else {
        conv4(sd, sdbuf, (blk - PB_X - PB_RT - 2 * PB_C) * 256 + tid);
    }
}

// Single-wave routing build: histogram -> bases -> tiles -> slots (+ slot_of inverse).
__global__ void route_build_kernel(const int* __restrict__ topi, const float* __restrict__ topw,
                                   int* __restrict__ token_ids, float* __restrict__ token_w,
                                   int* __restrict__ slot_of,
                                   int* __restrict__ tile_e, int* __restrict__ tile_k) {
    __shared__ int h[64][NREG];
    __shared__ int bases[NREG];
    __shared__ int cur[64][NREG];
    const int lane = threadIdx.x;   // 0..63, single wave

    for (int i = lane; i < CAP_SLOTS; i += 64) token_ids[i] = -1;

#pragma unroll
    for (int r = 0; r < NREG; r++) h[lane][r] = 0;
    for (int i = 0; i < T_TOK * 2 / 64; i++) {
        int entry = i * 64 + lane;
        int r = topi[entry] * 2 + (entry & 1);
        h[lane][r]++;
    }
    __syncthreads();

    if (lane < NREG) {
        int c = 0;
        for (int l = 0; l < 64; l++) c += h[l][lane];
        bases[lane] = c;
    }
    __syncthreads();

    if (lane == 0) {
        int b = 0, t = 0;
        for (int r = 0; r < NREG; r++) {
            int c = bases[r];
            int nt = (c + 127) >> 7;
            bases[r] = b;
            for (int i = 0; i < nt; i++) { tile_e[t] = r >> 1; tile_k[t] = r & 1; t++; }
            b += nt << 7;
        }
        for (; t < MAX_TILES; t++) { tile_e[t] = -1; tile_k[t] = -1; }
    }
    __syncthreads();

    for (int r = 0; r < NREG; r++) {
        int s = bases[r];
        for (int l = 0; l < lane; l++) s += h[l][r];
        cur[lane][r] = s;
    }
    __syncthreads();

    for (int i = 0; i < T_TOK * 2 / 64; i++) {
        int entry = i * 64 + lane;
        int r = topi[entry] * 2 + (entry & 1);
        int slot = cur[lane][r]++;
        token_ids[slot] = entry >> 1;
        token_w[slot] = topw[entry];
        slot_of[entry] = slot;
    }
}

// out[t][h] += w0*r_out[s0][h] + w1*r_out[s1][h]
__global__ void combine_kernel(float* __restrict__ out, const __bf16* __restrict__ r_out,
                               const int* __restrict__ slot_of, const float* __restrict__ topw) {
    int gid = blockIdx.x * 256 + threadIdx.x;
    int t = gid >> 8;
    int hcol = (gid & 255) * 4;
    int s0 = slot_of[t * 2], s1 = slot_of[t * 2 + 1];
    float w0 = topw[t * 2], w1 = topw[t * 2 + 1];
    bf16x4 a = *(const bf16x4*)&r_out[(size_t)s0 * H_DIM + hcol];
    bf16x4 b = *(const bf16x4*)&r_out[(size_t)s1 * H_DIM + hcol];
    float4 o = *(float4*)&out[(size_t)t * H_DIM + hcol];
    o.x += w0 * (float)a[0] + w1 * (float)b[0];
    o.y += w0 * (float)a[1] + w1 * (float)b[1];
    o.z += w0 * (float)a[2] + w1 * (float)b[2];
    o.w += w0 * (float)a[3] + w1 * (float)b[3];
    *(float4*)&out[(size_t)t * H_DIM + hcol] = o;
}

// Fused gate+up GEMM (R8-proven): 128x128, BK=32, 8 waves of 64x32 on both mats.
template<int K>
__global__ __launch_bounds__(512, 3)
void gateup_fused(const __bf16* __restrict__ A,
                  const __bf16* __restrict__ Wg, const __bf16* __restrict__ Wu,
                  __bf16* __restrict__ hid,
                  const int* __restrict__ token_ids, const int* __restrict__ tile_e) {
    int bx = blockIdx.x, by = blockIdx.y;
    swz_tile(bx, by);
    int e = 0;
    if (tile_e) { e = tile_e[bx]; if (e < 0) return; }
    const int m0 = bx * 128, n0 = by * 128;

    __shared__ __bf16 As[2][128 * 32];
    __shared__ __bf16 Bg[2][128 * 32];
    __shared__ __bf16 Bu[2][128 * 32];

    const int tid = threadIdx.x, lane = tid & 63, wid = tid >> 6;
    const int wm = wid >> 2, wn = wid & 3;

    const int srow = tid >> 2;
    const int colb = (tid & 3) * 16;

    int ar;
    if (tile_e) {
        int t0 = token_ids[m0 + srow];
        ar = t0 < 0 ? 0 : t0;
    } else {
        ar = m0 + srow;
    }
    const char* pA = (const char*)A + (size_t)ar * (K * 2) + colb;
    const char* pG = (const char*)Wg + ((size_t)e * I_DIM + n0 + srow) * (K * 2) + colb;
    const char* pU = (const char*)Wu + ((size_t)e * I_DIM + n0 + srow) * (K * 2) + colb;
    const int ldsoff = wid * 1024;

    f32x4 accg[4][2], accu[4][2];
    const f32x4 z4 = {0.f, 0.f, 0.f, 0.f};
#pragma unroll
    for (int i = 0; i < 4; i++)
#pragma unroll
        for (int j = 0; j < 2; j++) { accg[i][j] = z4; accu[i][j] = z4; }

    constexpr int NT = K / 32;

    auto stage = [&](int buf, int kt) {
        const size_t ko = (size_t)kt * 64;
        gload_lds16(pA + ko, (char*)As[buf] + ldsoff);
        gload_lds16(pG + ko, (char*)Bg[buf] + ldsoff);
        gload_lds16(pU + ko, (char*)Bu[buf] + ldsoff);
    };

    auto compute = [&](int buf) {
        const int rA = wm * 64 + (lane & 15);
        const int rB = wn * 32 + (lane & 15);
        const int cK = (lane >> 4) * 8;
        bf16x8 a[4], g[2], u[2];
#pragma unroll
        for (int i = 0; i < 4; i++) a[i] = *(const bf16x8*)&As[buf][(rA + i * 16) * 32 + cK];
#pragma unroll
        for (int j = 0; j < 2; j++) {
            g[j] = *(const bf16x8*)&Bg[buf][(rB + j * 16) * 32 + cK];
            u[j] = *(const bf16x8*)&Bu[buf][(rB + j * 16) * 32 + cK];
        }
#pragma unroll
        for (int i = 0; i < 4; i++)
#pragma unroll
            for (int j = 0; j < 2; j++) {
                accg[i][j] = __builtin_amdgcn_mfma_f32_16x16x32_bf16(a[i], g[j], accg[i][j], 0, 0, 0);
                accu[i][j] = __builtin_amdgcn_mfma_f32_16x16x32_bf16(a[i], u[j], accu[i][j], 0, 0, 0);
            }
    };

    stage(0, 0);
    __syncthreads();
    int cur = 0;
    for (int kt = 0; kt < NT; ++kt) {
        if (kt + 1 < NT) stage(cur ^ 1, kt + 1);
        compute(cur);
        __syncthreads();
        cur ^= 1;
    }

    const int cb = lane & 15, rb = (lane >> 4) * 4;
#pragma unroll
    for (int i = 0; i < 4; i++)
#pragma unroll
        for (int j = 0; j < 2; j++)
#pragma unroll
            for (int r = 0; r < 4; r++) {
                const int row = wm * 64 + i * 16 + rb + r;
                const int col = n0 + wn * 32 + j * 16 + cb;
                float gv = accg[i][j][r];
                float uv = accu[i][j][r];
                float h = (gv / (1.0f + __expf(-gv))) * uv;
                hid[(size_t)(m0 + row) * I_DIM + col] = (__bf16)h;
            }
}

// Down GEMM, K=I_DIM. MODE 0: shared (B=sdw, f32 out direct, no tile table).
// MODE 1: routed (B=ed + e offset, bf16 slot rows into r_out).
template<int MODE>
__global__ __launch_bounds__(256, 4)
void down_kernel(const __bf16* __restrict__ A, const __bf16* __restrict__ B,
                 __bf16* __restrict__ r_out, float* __restrict__ out,
                 const int* __restrict__ tile_e) {
    int bx = blockIdx.x, by = blockIdx.y;
    swz_tile(bx, by);
    int e = 0;
    if (MODE == 1) { e = tile_e[bx]; if (e < 0) return; }
    const int m0 = bx * 128, n0 = by * 128;

    __shared__ __bf16 As[2][128 * 32];
    __shared__ __bf16 Bs[2][128 * 32];

    const int tid = threadIdx.x, lane = tid & 63, wid = tid >> 6;
    const int wm = wid >> 1, wn = wid & 1;
    const int srow = wid * 16 + (lane >> 2);
    const int colb = (lane & 3) * 16;

    const char* pA0 = (const char*)A + (size_t)(m0 + srow) * (I_DIM * 2) + colb;
    const char* pA1 = (const char*)A + (size_t)(m0 + srow + 64) * (I_DIM * 2) + colb;
    const char* pB0 = (const char*)B + ((size_t)e * H_DIM + n0 + srow) * (I_DIM * 2) + colb;
    const char* pB1 = pB0 + (size_t)64 * (I_DIM * 2);
    const int ldsoff = wid * 1024;

    f32x4 acc[4][4];
    const f32x4 z4 = {0.f, 0.f, 0.f, 0.f};
#pragma unroll
    for (int i = 0; i < 4; i++)
#pragma unroll
        for (int j = 0; j < 4; j++) acc[i][j] = z4;

    constexpr int NT = I_DIM / 32;
    auto stage = [&](int buf, int kt) {
        const size_t ko = (size_t)kt * 64;
        char* a_l = (char*)As[buf] + ldsoff;
        gload_lds16(pA0 + ko, a_l);
        gload_lds16(pA1 + ko, a_l + 4096);
        char* b_l = (char*)Bs[buf] + ldsoff;
        gload_lds16(pB0 + ko, b_l);
        gload_lds16(pB1 + ko, b_l + 4096);
    };
    auto compute = [&](int buf) {
        const int rA = wm * 64 + (lane & 15);
        const int rB = wn * 64 + (lane & 15);
        const int cK = (lane >> 4) * 8;
        bf16x8 a[4], b[4];
#pragma unroll
        for (int i = 0; i < 4; i++) a[i] = *(const bf16x8*)&As[buf][(rA + i * 16) * 32 + cK];
#pragma unroll
        for (int j = 0; j < 4; j++) b[j] = *(const bf16x8*)&Bs[buf][(rB + j * 16) * 32 + cK];
#pragma unroll
        for (int i = 0; i < 4; i++)
#pragma unroll
            for (int j = 0; j < 4; j++)
                acc[i][j] = __builtin_amdgcn_mfma_f32_16x16x32_bf16(a[i], b[j], acc[i][j], 0, 0, 0);
    };

    stage(0, 0);
    __syncthreads();
    int cur = 0;
    for (int kt = 0; kt < NT; ++kt) {
        if (kt + 1 < NT) stage(cur ^ 1, kt + 1);
        compute(cur);
        __syncthreads();
        cur ^= 1;
    }

    const int cb = lane & 15, rb = (lane >> 4) * 4;
#pragma unroll
    for (int i = 0; i < 4; i++)
#pragma unroll
        for (int j = 0; j < 4; j++)
#pragma unroll
            for (int r = 0; r < 4; r++) {
                const int row = wm * 64 + i * 16 + rb + r;
                const int col = n0 + wn * 64 + j * 16 + cb;
                if (MODE == 0) out[(size_t)(m0 + row) * H_DIM + col] = acc[i][j][r];
                else r_out[(size_t)(m0 + row) * H_DIM + col] = (__bf16)acc[i][j][r];
            }
}

extern "C" void kernel_launch(void* const* d_in, const int* in_sizes, int n_in,
                              void* d_out, int out_size, void* d_ws, size_t ws_size,
                              hipStream_t stream) {
    const float* x = (const float*)d_in[0];
    const float* gate_w = (const float*)d_in[1];
    const float* expert_gate = (const float*)d_in[2];
    const float* expert_up = (const float*)d_in[3];
    const float* expert_down = (const float*)d_in[4];
    const float* shared_gate = (const float*)d_in[5];
    const float* shared_up = (const float*)d_in[6];
    const float* shared_down = (const float*)d_in[7];
    float* out = (float*)d_out;

    char* w = (char*)d_ws;
    size_t off = 0;
    auto alloc = [&](size_t bytes) {
        void* p = w + off;
        off = (off + bytes + 255) & ~(size_t)255;
        return p;
    };

    // Layout identical to R9/R10 (~214 MB, proven).
    const size_t wsz = (size_t)N_EXP * I_DIM * H_DIM * 2;   // 46.1 MB
    __bf16* xb = (__bf16*)alloc((size_t)T_TOK * H_DIM * 2);
    __bf16* wbufA = (__bf16*)alloc(wsz);
    __bf16* hid = (__bf16*)alloc((size_t)CAP_SLOTS * I_DIM * 2);
    int* topi = (int*)alloc((size_t)T_TOK * 2 * 4);
    float* topw = (float*)alloc((size_t)T_TOK * 2 * 4);
    int* slot_of = (int*)alloc((size_t)T_TOK * 2 * 4);
    int* tile_e = (int*)alloc(MAX_TILES * 4);
    int* tile_k = (int*)alloc(MAX_TILES * 4);
    int* token_ids = (int*)alloc((size_t)CAP_SLOTS * 4);
    float* token_w = (float*)alloc((size_t)CAP_SLOTS * 4);
    __bf16* wbufB = (__bf16*)alloc(wsz);
    __bf16* r_out = wbufB;                                  // eu dead after routed gateup
    __bf16* sdbuf = hid + (size_t)SD_ROW * I_DIM;           // sd parked in hid rows

    const int nE4 = N_EXP * I_DIM * H_DIM / 4;

    // 1) prep: x-conv | router | sg | su | sd  (one lean dispatch)
    prep_kernel<<<PB_X + PB_RT + 3 * PB_C, 256, 0, stream>>>(
        x, gate_w, xb, topi, topw, shared_gate, shared_up, shared_down,
        wbufA, wbufB, sdbuf);

    // 2) routing build
    route_build_kernel<<<1, 64, 0, stream>>>(topi, topw, token_ids, token_w, slot_of, tile_e, tile_k);

    // 3) shared gate+up (wbufA=sg, wbufB=su; identity rows)
    gateup_fused<H_DIM><<<dim3(T_TOK / 128, I_DIM / 128), 512, 0, stream>>>(
        xb, wbufA, wbufB, hid, nullptr, nullptr);

    // 4) eg/eu -> bf16 (lean, no LDS); overwrites sg/su (dead after step 3)
    conv2_kernel<<<2 * (nE4 / 256), 256, 0, stream>>>(expert_gate, wbufA, nE4, expert_up, wbufB, nE4);

    // 5) shared down: reads hid[0..8192) + sdbuf, writes f32 out directly
    down_kernel<0><<<dim3(T_TOK / 128, H_DIM / 128), 256, 0, stream>>>(
        hid, sdbuf, nullptr, out, nullptr);

    // 6) routed gate+up (gathered rows; overwrites hid slot rows incl. sdbuf region)
    gateup_fused<H_DIM><<<dim3(MAX_TILES, I_DIM / 128), 512, 0, stream>>>(
        xb, wbufA, wbufB, hid, token_ids, tile_e);

    // 7) expert_down -> bf16 (wbufA free: eg dead)
    conv_kernel<<<nE4 / 256, 256, 0, stream>>>(expert_down, wbufA, nE4);

    // 8) routed down -> r_out slot rows (single pass, no atomics)
    down_kernel<1><<<dim3(MAX_TILES, H_DIM / 128), 256, 0, stream>>>(
        hid, wbufA, r_out, nullptr, tile_e);

    // 9) combine: out += w0*r0 + w1*r1
    combine_kernel<<<T_TOK * H_DIM / 1024, 256, 0, stream>>>(out, r_out, slot_of, topw);
}